// Round 2
// baseline (782.578 us; speedup 1.0000x reference)
//
#include <hip/hip_runtime.h>
#include <math.h>

// Problem constants: R=1024, C=8192, DIN=16, E=5, NREG=2048
#define RDIM 1024
#define CDIM 8192
#define DIN  16
#define EDIM 5

// Tile: 16 regions x 256 cells per block, 256 threads (4 waves)
#define RT   16
#define CT   256
// Per-region LDS row: W1^T at [e*16+i] (0..79), b1 at 80..84, Wf at 88..92, pad to 96
#define WROW 96

typedef float fv4 __attribute__((ext_vector_type(4)));   // native vector: OK for nontemporal builtins

__global__ __launch_bounds__(256, 4)
void e2e_kernel(const float* __restrict__ emb,   // [R, C, DIN]
                const int*   __restrict__ gidx,  // [R]
                const float* __restrict__ W1,    // [NREG, DIN, E]
                const float* __restrict__ b1,    // [NREG, E]
                const float* __restrict__ Wf,    // [NREG, E]
                float* __restrict__ out)         // [C, R]
{
    __shared__ __align__(16) float s_w[RT * WROW];      // 6 KiB
    __shared__ float s_tile[CT * (RT + 1)];             // 17 KiB, stride 17 -> 2-way alias (free)

    const int tid = threadIdx.x;
    const int c0  = blockIdx.x * CT;
    const int r0  = blockIdx.y * RT;

    // Stage gathered weights, W1 TRANSPOSED to [e][i] so the compute loop can
    // hoist just 16 weights per e-step (4x ds_read_b128, wave-uniform broadcast).
    for (int idx = tid; idx < RT * 90; idx += 256) {
        const int rl = idx / 90;
        const int k  = idx - rl * 90;
        const int g  = gidx[r0 + rl];       // small, L2-hit; avoids a staging barrier
        float v; int dst;
        if (k < 80) {
            const int e = k >> 4, i = k & 15;
            v = W1[g * 80 + i * EDIM + e];  // transpose on the fly
            dst = k;                        // [e*16 + i]
        } else if (k < 85) {
            v = b1[g * EDIM + (k - 80)];    dst = k;
        } else {
            v = Wf[g * EDIM + (k - 85)];    dst = k + 3;   // 88..92
        }
        s_w[rl * WROW + dst] = v;
    }
    __syncthreads();

    const int lane = tid & 63;
    const int wv   = tid >> 6;

    // Each wave handles 4 regions; each lane handles 4 cells per region.
    #pragma unroll
    for (int q = 0; q < 4; ++q) {
        const int rl = wv * 4 + q;
        const int r  = r0 + rl;

        // Batch all 16 nontemporal loads (4 cells x 64B) before any compute:
        // 16 KB/wave in flight, no cache pollution (stream is read-once).
        const fv4* p0 = (const fv4*)(emb + ((size_t)r * CDIM + c0 + lane) * DIN);
        float x[4][DIN];
        #pragma unroll
        for (int m = 0; m < 4; ++m) {
            const fv4* p = p0 + m * 64 * 4;   // +64 cells = 256 float4
            fv4 t0 = __builtin_nontemporal_load(p + 0);
            fv4 t1 = __builtin_nontemporal_load(p + 1);
            fv4 t2 = __builtin_nontemporal_load(p + 2);
            fv4 t3 = __builtin_nontemporal_load(p + 3);
            x[m][ 0]=t0.x; x[m][ 1]=t0.y; x[m][ 2]=t0.z; x[m][ 3]=t0.w;
            x[m][ 4]=t1.x; x[m][ 5]=t1.y; x[m][ 6]=t1.z; x[m][ 7]=t1.w;
            x[m][ 8]=t2.x; x[m][ 9]=t2.y; x[m][10]=t2.z; x[m][11]=t2.w;
            x[m][12]=t3.x; x[m][13]=t3.y; x[m][14]=t3.z; x[m][15]=t3.w;
        }

        const float* wrow = s_w + rl * WROW;
        float bb[EDIM], wf[EDIM];
        #pragma unroll
        for (int e = 0; e < EDIM; ++e) { bb[e] = wrow[80 + e]; wf[e] = wrow[88 + e]; }

        float acc[4] = {0.f, 0.f, 0.f, 0.f};

        // e-outer: only 16 weight floats live at a time (vs 80 before).
        #pragma unroll
        for (int e = 0; e < EDIM; ++e) {
            const fv4* wt = (const fv4*)(wrow + e * 16);
            const fv4 w0 = wt[0], w1 = wt[1], w2 = wt[2], w3 = wt[3];

            float h[4];
            #pragma unroll
            for (int m = 0; m < 4; ++m) {
                float hh = bb[e];
                hh = fmaf(x[m][ 0], w0.x, hh);
                hh = fmaf(x[m][ 1], w0.y, hh);
                hh = fmaf(x[m][ 2], w0.z, hh);
                hh = fmaf(x[m][ 3], w0.w, hh);
                hh = fmaf(x[m][ 4], w1.x, hh);
                hh = fmaf(x[m][ 5], w1.y, hh);
                hh = fmaf(x[m][ 6], w1.z, hh);
                hh = fmaf(x[m][ 7], w1.w, hh);
                hh = fmaf(x[m][ 8], w2.x, hh);
                hh = fmaf(x[m][ 9], w2.y, hh);
                hh = fmaf(x[m][10], w2.z, hh);
                hh = fmaf(x[m][11], w2.w, hh);
                hh = fmaf(x[m][12], w3.x, hh);
                hh = fmaf(x[m][13], w3.y, hh);
                hh = fmaf(x[m][14], w3.z, hh);
                hh = fmaf(x[m][15], w3.w, hh);
                h[m] = hh;
            }
            #pragma unroll
            for (int m = 0; m < 4; ++m) {
                float hh = h[m];
                // exact GELU: 0.5*x*(1+erf(x/sqrt(2))) -- same math/order as baseline
                hh = 0.5f * hh * (1.0f + erff(hh * 0.70710678118654752f));
                acc[m] = fmaf(hh, wf[e], acc[m]);
            }
        }

        #pragma unroll
        for (int m = 0; m < 4; ++m)
            s_tile[(lane + 64 * m) * (RT + 1) + rl] = acc[m];
    }
    __syncthreads();

    // Transposed, coalesced, nontemporal write-out: out[(c0+cl)*R + r0 + rl]
    const int orl  = tid & 15;
    const int ocl0 = tid >> 4;   // 0..15
    #pragma unroll
    for (int it = 0; it < 16; ++it) {
        const int cl = ocl0 + 16 * it;
        __builtin_nontemporal_store(s_tile[cl * (RT + 1) + orl],
                                    &out[(size_t)(c0 + cl) * RDIM + r0 + orl]);
    }
}

extern "C" void kernel_launch(void* const* d_in, const int* in_sizes, int n_in,
                              void* d_out, int out_size, void* d_ws, size_t ws_size,
                              hipStream_t stream) {
    const float* emb  = (const float*)d_in[0];
    const int*   gidx = (const int*)d_in[1];
    const float* W1   = (const float*)d_in[2];
    const float* b1   = (const float*)d_in[3];
    const float* Wf   = (const float*)d_in[4];
    float* out = (float*)d_out;

    dim3 grid(CDIM / CT, RDIM / RT);   // 32 x 64 = 2048 blocks
    dim3 block(256);
    e2e_kernel<<<grid, block, 0, stream>>>(emb, gidx, W1, b1, Wf, out);
}

// Round 3
// 714.185 us; speedup vs baseline: 1.0958x; 1.0958x over previous
//
#include <hip/hip_runtime.h>
#include <math.h>

// Problem constants: R=1024, C=8192, DIN=16, E=5, NREG=2048
#define RDIM 1024
#define CDIM 8192
#define DIN  16
#define EDIM 5

// Tile: 16 regions x 256 cells per block, 256 threads (4 waves)
#define RT   16
#define CT   256
// Per-region LDS row: W1^T at [e*16+i] (0..79), b1 at 80..84, Wf at 88..92, pad to 96
#define WROW 96

typedef float fv4 __attribute__((ext_vector_type(4)));

__global__ __launch_bounds__(256)
void e2e_kernel(const float* __restrict__ emb,   // [R, C, DIN]
                const int*   __restrict__ gidx,  // [R]
                const float* __restrict__ W1,    // [NREG, DIN, E]
                const float* __restrict__ b1,    // [NREG, E]
                const float* __restrict__ Wf,    // [NREG, E]
                float* __restrict__ out)         // [C, R]
{
    __shared__ __align__(16) float s_w[RT * WROW];      // 6 KiB
    __shared__ float s_tile[CT * (RT + 1)];             // 17 KiB, stride 17 -> 2-way alias (free)

    const int tid = threadIdx.x;
    const int c0  = blockIdx.x * CT;
    const int r0  = blockIdx.y * RT;

    // Stage gathered weights, W1 TRANSPOSED to [e][i] so the compute loop can
    // hoist just 16 weights per e-step (4x ds_read_b128, wave-uniform broadcast).
    for (int idx = tid; idx < RT * 90; idx += 256) {
        const int rl = idx / 90;
        const int k  = idx - rl * 90;
        const int g  = gidx[r0 + rl];       // small, L2-hit; avoids a staging barrier
        float v; int dst;
        if (k < 80) {
            const int e = k >> 4, i = k & 15;
            v = W1[g * 80 + i * EDIM + e];  // transpose on the fly
            dst = k;                        // [e*16 + i]
        } else if (k < 85) {
            v = b1[g * EDIM + (k - 80)];    dst = k;
        } else {
            v = Wf[g * EDIM + (k - 85)];    dst = k + 3;   // 88..92
        }
        s_w[rl * WROW + dst] = v;
    }
    __syncthreads();

    const int lane = tid & 63;
    const int wv   = tid >> 6;

    // Each wave handles 4 regions; each lane handles 4 cells per region.
    #pragma unroll
    for (int q = 0; q < 4; ++q) {
        const int rl = wv * 4 + q;
        const int r  = r0 + rl;

        // Batch all 16 CACHED loads (4 cells x 64B) before any compute.
        // NOTE: plain loads, NOT nontemporal -- the per-iteration input restore
        // leaves a large slice of emb L3-resident; nt loads forfeited those hits
        // (round-2 regression, +64 us).
        const fv4* p0 = (const fv4*)(emb + ((size_t)r * CDIM + c0 + lane) * DIN);
        float x[4][DIN];
        #pragma unroll
        for (int m = 0; m < 4; ++m) {
            const fv4* p = p0 + m * 64 * 4;   // +64 cells = 256 float4
            fv4 t0 = p[0];
            fv4 t1 = p[1];
            fv4 t2 = p[2];
            fv4 t3 = p[3];
            x[m][ 0]=t0.x; x[m][ 1]=t0.y; x[m][ 2]=t0.z; x[m][ 3]=t0.w;
            x[m][ 4]=t1.x; x[m][ 5]=t1.y; x[m][ 6]=t1.z; x[m][ 7]=t1.w;
            x[m][ 8]=t2.x; x[m][ 9]=t2.y; x[m][10]=t2.z; x[m][11]=t2.w;
            x[m][12]=t3.x; x[m][13]=t3.y; x[m][14]=t3.z; x[m][15]=t3.w;
        }

        const float* wrow = s_w + rl * WROW;
        float bb[EDIM], wf[EDIM];
        #pragma unroll
        for (int e = 0; e < EDIM; ++e) { bb[e] = wrow[80 + e]; wf[e] = wrow[88 + e]; }

        float acc[4] = {0.f, 0.f, 0.f, 0.f};

        // e-outer: only 16 weight floats live at a time (vs 80 before).
        #pragma unroll
        for (int e = 0; e < EDIM; ++e) {
            const fv4* wt = (const fv4*)(wrow + e * 16);
            const fv4 w0 = wt[0], w1 = wt[1], w2 = wt[2], w3 = wt[3];

            float h[4];
            #pragma unroll
            for (int m = 0; m < 4; ++m) {
                float hh = bb[e];
                hh = fmaf(x[m][ 0], w0.x, hh);
                hh = fmaf(x[m][ 1], w0.y, hh);
                hh = fmaf(x[m][ 2], w0.z, hh);
                hh = fmaf(x[m][ 3], w0.w, hh);
                hh = fmaf(x[m][ 4], w1.x, hh);
                hh = fmaf(x[m][ 5], w1.y, hh);
                hh = fmaf(x[m][ 6], w1.z, hh);
                hh = fmaf(x[m][ 7], w1.w, hh);
                hh = fmaf(x[m][ 8], w2.x, hh);
                hh = fmaf(x[m][ 9], w2.y, hh);
                hh = fmaf(x[m][10], w2.z, hh);
                hh = fmaf(x[m][11], w2.w, hh);
                hh = fmaf(x[m][12], w3.x, hh);
                hh = fmaf(x[m][13], w3.y, hh);
                hh = fmaf(x[m][14], w3.z, hh);
                hh = fmaf(x[m][15], w3.w, hh);
                h[m] = hh;
            }
            #pragma unroll
            for (int m = 0; m < 4; ++m) {
                float hh = h[m];
                // exact GELU: 0.5*x*(1+erf(x/sqrt(2))) -- same math/order as baseline
                hh = 0.5f * hh * (1.0f + erff(hh * 0.70710678118654752f));
                acc[m] = fmaf(hh, wf[e], acc[m]);
            }
        }

        #pragma unroll
        for (int m = 0; m < 4; ++m)
            s_tile[(lane + 64 * m) * (RT + 1) + rl] = acc[m];
    }
    __syncthreads();

    // Transposed, coalesced write-out: out[(c0+cl)*R + r0 + rl].
    // Nontemporal store: write-once output, keeps emb resident in L2/L3.
    const int orl  = tid & 15;
    const int ocl0 = tid >> 4;   // 0..15
    #pragma unroll
    for (int it = 0; it < 16; ++it) {
        const int cl = ocl0 + 16 * it;
        __builtin_nontemporal_store(s_tile[cl * (RT + 1) + orl],
                                    &out[(size_t)(c0 + cl) * RDIM + r0 + orl]);
    }
}

extern "C" void kernel_launch(void* const* d_in, const int* in_sizes, int n_in,
                              void* d_out, int out_size, void* d_ws, size_t ws_size,
                              hipStream_t stream) {
    const float* emb  = (const float*)d_in[0];
    const int*   gidx = (const int*)d_in[1];
    const float* W1   = (const float*)d_in[2];
    const float* b1   = (const float*)d_in[3];
    const float* Wf   = (const float*)d_in[4];
    float* out = (float*)d_out;

    dim3 grid(CDIM / CT, RDIM / RT);   // 32 x 64 = 2048 blocks
    dim3 block(256);
    e2e_kernel<<<grid, block, 0, stream>>>(emb, gidx, W1, b1, Wf, out);
}